// Round 1
// baseline (3879.860 us; speedup 1.0000x reference)
//
#include <hip/hip_runtime.h>

#define N_NODES 100000
#define F_IN 128
#define HID 64
#define OUT_F 300

// ---------------------------------------------------------------- zero scratch
__global__ void k_zero(float* __restrict__ agg, int* __restrict__ cnt) {
    int gid = blockIdx.x * blockDim.x + threadIdx.x;
    int stride = gridDim.x * blockDim.x;
    const int total = N_NODES * F_IN;
    for (int j = gid; j < total; j += stride) agg[j] = 0.0f;
    for (int j = gid; j < N_NODES; j += stride) cnt[j] = 0;
}

// ---------------------------------------------------------------- edge scatter
// 32 threads per edge; each thread atomically adds one float4 (4 floats) of the
// source node's feature row into the destination accumulator.
__global__ void k_scatter(const float* __restrict__ x, const int* __restrict__ ei,
                          float* __restrict__ agg, int* __restrict__ cnt, int nE) {
    int gid = blockIdx.x * blockDim.x + threadIdx.x;
    int stride = gridDim.x * blockDim.x;
    int lane = gid & 31;
    for (int e = gid >> 5; e < nE; e += stride >> 5) {
        int src = ei[e];        // row 0 of edge_index
        int dst = ei[nE + e];   // row 1 of edge_index
        const float4* xr = (const float4*)(x + (size_t)src * F_IN);
        float4 v = xr[lane];
        float* ar = agg + (size_t)dst * F_IN + lane * 4;
        atomicAdd(ar + 0, v.x);
        atomicAdd(ar + 1, v.y);
        atomicAdd(ar + 2, v.z);
        atomicAdd(ar + 3, v.w);
        if (lane == 0) atomicAdd(cnt + dst, 1);
    }
}

// ---------------------------------------------------------------- fused node op
// One thread per node. All weight accesses are wave-uniform -> scalar loads.
// h[64] kept in VGPRs (f-loop fully unrolled so indices are compile-time).
__global__ __launch_bounds__(256) void k_node(
    const float* __restrict__ x, const float* __restrict__ agg,
    const int* __restrict__ cnt,
    const float* __restrict__ Wl, const float* __restrict__ bl,
    const float* __restrict__ Wr, const float* __restrict__ Wout,
    const float* __restrict__ bout, float* __restrict__ out) {
    int n = blockIdx.x * blockDim.x + threadIdx.x;
    if (n >= N_NODES) return;

    float h[HID];
#pragma unroll
    for (int f = 0; f < HID; ++f) h[f] = bl[f];

    float inv = 1.0f / fmaxf((float)cnt[n], 1.0f);

    // K in chunks of 32 to bound register pressure.
    for (int kc = 0; kc < F_IN; kc += 32) {
        float xr[32], mr[32];
        const float4* xp = (const float4*)(x + (size_t)n * F_IN + kc);
        const float4* ap = (const float4*)(agg + (size_t)n * F_IN + kc);
#pragma unroll
        for (int q = 0; q < 8; ++q) {
            float4 xv = xp[q];
            float4 av = ap[q];
            xr[q * 4 + 0] = xv.x; xr[q * 4 + 1] = xv.y;
            xr[q * 4 + 2] = xv.z; xr[q * 4 + 3] = xv.w;
            mr[q * 4 + 0] = av.x * inv; mr[q * 4 + 1] = av.y * inv;
            mr[q * 4 + 2] = av.z * inv; mr[q * 4 + 3] = av.w * inv;
        }
#pragma unroll
        for (int f = 0; f < HID; ++f) {
            const float* wl = Wl + f * F_IN + kc;   // uniform -> s_load
            const float* wr = Wr + f * F_IN + kc;   // uniform -> s_load
            float a = h[f];
#pragma unroll
            for (int k = 0; k < 32; ++k) {
                a = fmaf(wl[k], mr[k], a);
                a = fmaf(wr[k], xr[k], a);
            }
            h[f] = a;
        }
    }
#pragma unroll
    for (int f = 0; f < HID; ++f) h[f] = fmaxf(h[f], 0.0f);

    // Output GEMM: 300 outputs in chunks of 20; Wout/bout uniform -> s_load.
    float* op = out + (size_t)n * OUT_F;
    for (int o = 0; o < OUT_F; o += 20) {
        float acc[20];
#pragma unroll
        for (int j = 0; j < 20; ++j) acc[j] = bout[o + j];
#pragma unroll
        for (int k = 0; k < HID; ++k) {
            float hv = h[k];
#pragma unroll
            for (int j = 0; j < 20; ++j)
                acc[j] = fmaf(Wout[(o + j) * HID + k], hv, acc[j]);
        }
#pragma unroll
        for (int j = 0; j < 20; ++j) op[o + j] = acc[j];
    }
}

extern "C" void kernel_launch(void* const* d_in, const int* in_sizes, int n_in,
                              void* d_out, int out_size, void* d_ws, size_t ws_size,
                              hipStream_t stream) {
    const float* x    = (const float*)d_in[0];
    const int*   ei   = (const int*)d_in[1];
    const float* Wl   = (const float*)d_in[2];
    const float* bl   = (const float*)d_in[3];
    const float* Wr   = (const float*)d_in[4];
    const float* Wout = (const float*)d_in[5];
    const float* bout = (const float*)d_in[6];
    float* out = (float*)d_out;

    float* agg = (float*)d_ws;                                   // 100000*128 f32 = 51.2 MB
    int*   cnt = (int*)((char*)d_ws + (size_t)N_NODES * F_IN * sizeof(float));

    int nE = in_sizes[1] / 2;

    k_zero<<<2048, 256, 0, stream>>>(agg, cnt);
    k_scatter<<<2048, 256, 0, stream>>>(x, ei, agg, cnt, nE);
    int nb = (N_NODES + 255) / 256;
    k_node<<<nb, 256, 0, stream>>>(x, agg, cnt, Wl, bl, Wr, Wout, bout, out);
}

// Round 2
// 1258.295 us; speedup vs baseline: 3.0834x; 3.0834x over previous
//
#include <hip/hip_runtime.h>

#define N_NODES 100000
#define F_IN 128
#define HID 64
#define OUT_F 300

// ------------------------------------------------------------------ zero cnt
__global__ void k_zero(int* __restrict__ cnt) {
    int i = blockIdx.x * blockDim.x + threadIdx.x;
    if (i < N_NODES) cnt[i] = 0;
}

// ------------------------------------------------------------------ histogram of dst
__global__ void k_hist(const int* __restrict__ ei, int* __restrict__ cnt, int nE) {
    int e = blockIdx.x * blockDim.x + threadIdx.x;
    if (e < nE) atomicAdd(cnt + ei[nE + e], 1);
}

// ------------------------------------------------------------------ exclusive scan (1 block)
__global__ __launch_bounds__(1024) void k_scan(const int* __restrict__ cnt,
                                               int* __restrict__ off,
                                               int* __restrict__ cursor) {
    __shared__ int wsum[16];
    __shared__ int carry;
    const int tid = threadIdx.x;
    const int lane = tid & 63;
    const int wid = tid >> 6;
    if (tid == 0) carry = 0;
    __syncthreads();
    for (int base = 0; base < N_NODES; base += 1024) {
        const int i = base + tid;
        int v = (i < N_NODES) ? cnt[i] : 0;
        int s = v;
#pragma unroll
        for (int d = 1; d < 64; d <<= 1) {
            int t = __shfl_up(s, d, 64);
            if (lane >= d) s += t;
        }
        if (lane == 63) wsum[wid] = s;
        __syncthreads();
        if (tid < 64) {
            int ws = (lane < 16) ? wsum[lane] : 0;
#pragma unroll
            for (int d = 1; d < 16; d <<= 1) {
                int t = __shfl_up(ws, d, 64);
                if (lane >= d) ws += t;
            }
            if (lane < 16) wsum[lane] = ws;
        }
        __syncthreads();
        int wexcl = (wid == 0) ? 0 : wsum[wid - 1];
        int total = wsum[15];
        int excl = carry + wexcl + (s - v);
        if (i < N_NODES) { off[i] = excl; cursor[i] = excl; }
        __syncthreads();
        if (tid == 0) carry += total;
        __syncthreads();
    }
}

// ------------------------------------------------------------------ CSR fill
__global__ void k_fill(const int* __restrict__ ei, int* __restrict__ cursor,
                       int* __restrict__ csr, int nE) {
    int e = blockIdx.x * blockDim.x + threadIdx.x;
    if (e < nE) {
        int src = ei[e];
        int dst = ei[nE + e];
        int pos = atomicAdd(cursor + dst, 1);
        csr[pos] = src;
    }
}

// ------------------------------------------------------------------ gather-aggregate (mean)
// One wave per node; lane owns 2 features (float2 -> 512B coalesced row read).
__global__ __launch_bounds__(256) void k_agg(const float* __restrict__ x,
                                             const int* __restrict__ csr,
                                             const int* __restrict__ off,
                                             const int* __restrict__ cnt,
                                             float* __restrict__ mean) {
    int n = (blockIdx.x * blockDim.x + threadIdx.x) >> 6;
    int lane = threadIdx.x & 63;
    if (n >= N_NODES) return;
    int begin = off[n];
    int deg = cnt[n];
    float ax = 0.f, ay = 0.f;
    int i = 0;
    for (; i + 4 <= deg; i += 4) {
        int s0 = csr[begin + i + 0];
        int s1 = csr[begin + i + 1];
        int s2 = csr[begin + i + 2];
        int s3 = csr[begin + i + 3];
        float2 v0 = ((const float2*)(x + (size_t)s0 * F_IN))[lane];
        float2 v1 = ((const float2*)(x + (size_t)s1 * F_IN))[lane];
        float2 v2 = ((const float2*)(x + (size_t)s2 * F_IN))[lane];
        float2 v3 = ((const float2*)(x + (size_t)s3 * F_IN))[lane];
        ax += v0.x + v1.x + v2.x + v3.x;
        ay += v0.y + v1.y + v2.y + v3.y;
    }
    for (; i < deg; ++i) {
        int s0 = csr[begin + i];
        float2 v0 = ((const float2*)(x + (size_t)s0 * F_IN))[lane];
        ax += v0.x; ay += v0.y;
    }
    float inv = 1.0f / fmaxf((float)deg, 1.0f);
    float2 r; r.x = ax * inv; r.y = ay * inv;
    ((float2*)(mean + (size_t)n * F_IN))[lane] = r;
}

// ------------------------------------------------------------------ fused node op
// 256 nodes/block (1 thread/node). x/mean staged via LDS in K-chunks of 16
// (coalesced global reads, 2-way-free LDS banks via pad 17). h[64] in VGPRs.
// Output in o-chunks of 20, staged via LDS for coalesced writes. Chunk loops
// are NOT unrolled -> icache-resident bodies.
#define KC 16
__global__ __launch_bounds__(256, 2) void k_node(
    const float* __restrict__ x, const float* __restrict__ mean,
    const float* __restrict__ Wl, const float* __restrict__ bl,
    const float* __restrict__ Wr, const float* __restrict__ Wout,
    const float* __restrict__ bout, float* __restrict__ out) {

    __shared__ float smem[2 * 256 * (KC + 1)];   // 34.8 KB; sout aliases front
    float* sx = smem;
    float* sm = smem + 256 * (KC + 1);

    const int tid = threadIdx.x;
    const int base = blockIdx.x * 256;
    const int n = base + tid;

    float h[HID];
#pragma unroll
    for (int f = 0; f < HID; ++f) h[f] = bl[f];

    for (int kc = 0; kc < F_IN; kc += KC) {
        __syncthreads();   // previous chunk's reads complete
        // stage 256 rows x 16 floats of x and mean, coalesced
#pragma unroll
        for (int it = 0; it < 4; ++it) {
            int idx = it * 256 + tid;          // float4 index, 1024 total
            int row = idx >> 2;
            int col = (idx & 3) << 2;
            int gn = base + row; if (gn >= N_NODES) gn = N_NODES - 1;
            float4 xv = *(const float4*)(x + (size_t)gn * F_IN + kc + col);
            float4 mv = *(const float4*)(mean + (size_t)gn * F_IN + kc + col);
            int la = row * (KC + 1) + col;
            sx[la + 0] = xv.x; sx[la + 1] = xv.y; sx[la + 2] = xv.z; sx[la + 3] = xv.w;
            sm[la + 0] = mv.x; sm[la + 1] = mv.y; sm[la + 2] = mv.z; sm[la + 3] = mv.w;
        }
        __syncthreads();
        float xr[KC], mr[KC];
#pragma unroll
        for (int k = 0; k < KC; ++k) {
            xr[k] = sx[tid * (KC + 1) + k];
            mr[k] = sm[tid * (KC + 1) + k];
        }
#pragma unroll
        for (int f = 0; f < HID; ++f) {
            const float* wl = Wl + f * F_IN + kc;   // uniform -> s_load
            const float* wr = Wr + f * F_IN + kc;
            float a = h[f];
#pragma unroll
            for (int k = 0; k < KC; ++k) {
                a = fmaf(wl[k], mr[k], a);
                a = fmaf(wr[k], xr[k], a);
            }
            h[f] = a;
        }
    }
#pragma unroll
    for (int f = 0; f < HID; ++f) h[f] = fmaxf(h[f], 0.0f);

    float* sout = smem;                           // 256*21 floats, aliases sx
    __syncthreads();                              // main-loop LDS reads done
    for (int o = 0; o < OUT_F; o += 20) {
        float acc[20];
#pragma unroll
        for (int j = 0; j < 20; ++j) acc[j] = bout[o + j];
#pragma unroll
        for (int k = 0; k < HID; ++k) {
            float hv = h[k];
#pragma unroll
            for (int j = 0; j < 20; ++j)
                acc[j] = fmaf(Wout[(o + j) * HID + k], hv, acc[j]);
        }
#pragma unroll
        for (int j = 0; j < 20; ++j) sout[tid * 21 + j] = acc[j];
        __syncthreads();
        // cooperative coalesced write of 256 rows x 20 floats
#pragma unroll
        for (int it = 0; it < 20; ++it) {
            int flat = it * 256 + tid;
            int r = flat / 20, c = flat % 20;
            int gn = base + r;
            if (gn < N_NODES) out[(size_t)gn * OUT_F + o + c] = sout[r * 21 + c];
        }
        __syncthreads();
    }
}

extern "C" void kernel_launch(void* const* d_in, const int* in_sizes, int n_in,
                              void* d_out, int out_size, void* d_ws, size_t ws_size,
                              hipStream_t stream) {
    const float* x    = (const float*)d_in[0];
    const int*   ei   = (const int*)d_in[1];
    const float* Wl   = (const float*)d_in[2];
    const float* bl   = (const float*)d_in[3];
    const float* Wr   = (const float*)d_in[4];
    const float* Wout = (const float*)d_in[5];
    const float* bout = (const float*)d_in[6];
    float* out = (float*)d_out;

    int nE = in_sizes[1] / 2;

    float* mean  = (float*)d_ws;                         // 51.2 MB
    int*   csr   = (int*)(mean + (size_t)N_NODES * F_IN);// 6.4 MB
    int*   cnt   = csr + nE;
    int*   off   = cnt + N_NODES;
    int*   cursor= off + N_NODES;

    int nbN = (N_NODES + 255) / 256;
    int nbE = (nE + 255) / 256;

    k_zero<<<nbN, 256, 0, stream>>>(cnt);
    k_hist<<<nbE, 256, 0, stream>>>(ei, cnt, nE);
    k_scan<<<1, 1024, 0, stream>>>(cnt, off, cursor);
    k_fill<<<nbE, 256, 0, stream>>>(ei, cursor, csr, nE);
    k_agg<<<(N_NODES * 64 + 255) / 256, 256, 0, stream>>>(x, csr, off, cnt, mean);
    k_node<<<nbN, 256, 0, stream>>>(x, mean, Wl, bl, Wr, Wout, bout, out);
}

// Round 3
// 349.331 us; speedup vs baseline: 11.1065x; 3.6020x over previous
//
#include <hip/hip_runtime.h>

#define N_NODES 100000
#define F_IN 128
#define HID 64
#define OUT_F 300
#define KCAT 256            // F_IN * 2 (mean | x)
#define WO_ROWS 320         // 300 padded to 20 tiles of 16

typedef short bf8 __attribute__((ext_vector_type(8)));
typedef float f32x4 __attribute__((ext_vector_type(4)));
typedef unsigned short us4 __attribute__((ext_vector_type(4)));

__device__ inline unsigned short f2bf(float f) {
    unsigned u = __builtin_bit_cast(unsigned, f);
    u += 0x7fff + ((u >> 16) & 1);          // round-to-nearest-even
    return (unsigned short)(u >> 16);
}
__device__ inline float b2f(unsigned short h) {
    return __builtin_bit_cast(float, (unsigned)h << 16);
}

// ------------------------------------------------------------------ zero cnt
__global__ void k_zero(int* __restrict__ cnt) {
    int i = blockIdx.x * blockDim.x + threadIdx.x;
    if (i < N_NODES) cnt[i] = 0;
}

// ------------------------------------------------------------------ histogram of dst
__global__ void k_hist(const int* __restrict__ ei, int* __restrict__ cnt, int nE) {
    int e = blockIdx.x * blockDim.x + threadIdx.x;
    if (e < nE) atomicAdd(cnt + ei[nE + e], 1);
}

// ------------------------------------------------------------------ scan: block sums
__global__ __launch_bounds__(1024) void k_scan1(const int* __restrict__ cnt,
                                                int* __restrict__ bsum) {
    __shared__ int ws[16];
    int i = blockIdx.x * 1024 + threadIdx.x;
    int v = (i < N_NODES) ? cnt[i] : 0;
#pragma unroll
    for (int d = 32; d > 0; d >>= 1) v += __shfl_down(v, d, 64);
    int lane = threadIdx.x & 63, wid = threadIdx.x >> 6;
    if (lane == 0) ws[wid] = v;
    __syncthreads();
    if (threadIdx.x < 16) {
        int t = ws[threadIdx.x];
#pragma unroll
        for (int d = 8; d > 0; d >>= 1) t += __shfl_down(t, d, 16);
        if (threadIdx.x == 0) bsum[blockIdx.x] = t;
    }
}

// ------------------------------------------------------------------ scan: scan of 98 block sums
__global__ void k_scan2(const int* __restrict__ bsum, int* __restrict__ bpre, int nb) {
    int lane = threadIdx.x;           // 64 threads, 1 block
    int carry = 0;
    for (int c = 0; c * 64 < nb; ++c) {
        int i = c * 64 + lane;
        int v = (i < nb) ? bsum[i] : 0;
        int s = v;
#pragma unroll
        for (int d = 1; d < 64; d <<= 1) { int t = __shfl_up(s, d, 64); if (lane >= d) s += t; }
        if (i < nb) bpre[i] = carry + s - v;
        carry += __shfl(s, 63, 64);
    }
}

// ------------------------------------------------------------------ scan: per-block exclusive
__global__ __launch_bounds__(1024) void k_scan3(const int* __restrict__ cnt,
                                                const int* __restrict__ bpre,
                                                int* __restrict__ off,
                                                int* __restrict__ cursor) {
    __shared__ int wsum[16];
    int tid = threadIdx.x, lane = tid & 63, wid = tid >> 6;
    int i = blockIdx.x * 1024 + tid;
    int v = (i < N_NODES) ? cnt[i] : 0;
    int s = v;
#pragma unroll
    for (int d = 1; d < 64; d <<= 1) { int t = __shfl_up(s, d, 64); if (lane >= d) s += t; }
    if (lane == 63) wsum[wid] = s;
    __syncthreads();
    if (tid < 16) {
        int wv = wsum[tid];
        int ps = wv;
#pragma unroll
        for (int d = 1; d < 16; d <<= 1) { int t = __shfl_up(ps, d, 16); if (tid >= d) ps += t; }
        wsum[tid] = ps - wv;          // exclusive
    }
    __syncthreads();
    int excl = bpre[blockIdx.x] + wsum[wid] + (s - v);
    if (i < N_NODES) { off[i] = excl; cursor[i] = excl; }
}

// ------------------------------------------------------------------ CSR fill
__global__ void k_fill(const int* __restrict__ ei, int* __restrict__ cursor,
                       int* __restrict__ csr, int nE) {
    int e = blockIdx.x * blockDim.x + threadIdx.x;
    if (e < nE) {
        int src = ei[e];
        int dst = ei[nE + e];
        int pos = atomicAdd(cursor + dst, 1);
        csr[pos] = src;
    }
}

// ------------------------------------------------------------------ x -> bf16 into A[:,128:256]
__global__ void k_cvt(const float* __restrict__ x, unsigned short* __restrict__ A) {
    int idx = blockIdx.x * blockDim.x + threadIdx.x;    // float4 index
    const int total = N_NODES * F_IN / 4;
    if (idx >= total) return;
    int n = idx >> 5;                                   // 32 float4 per row
    int c4 = idx & 31;
    float4 v = ((const float4*)x)[idx];
    us4 r; r[0] = f2bf(v.x); r[1] = f2bf(v.y); r[2] = f2bf(v.z); r[3] = f2bf(v.w);
    *reinterpret_cast<us4*>(A + (size_t)n * KCAT + F_IN + c4 * 4) = r;
}

// ------------------------------------------------------------------ weights -> bf16
__global__ void k_wcvt(const float* __restrict__ Wl, const float* __restrict__ Wr,
                       const float* __restrict__ Wout,
                       unsigned short* __restrict__ Wc, unsigned short* __restrict__ Wo) {
    int idx = blockIdx.x * blockDim.x + threadIdx.x;
    if (idx < HID * KCAT) {                              // 16384
        int f = idx >> 8, k = idx & 255;
        float v = (k < F_IN) ? Wl[f * F_IN + k] : Wr[f * F_IN + (k - F_IN)];
        Wc[idx] = f2bf(v);
    } else {
        int j = idx - HID * KCAT;                        // 0 .. 20479
        if (j < WO_ROWS * HID) {
            int o = j >> 6, k = j & 63;
            Wo[j] = (o < OUT_F) ? f2bf(Wout[o * HID + k]) : (unsigned short)0;
        }
    }
}

// ------------------------------------------------------------------ gather-aggregate (mean, bf16)
// One wave per node; lane owns 2 features (dword -> 256B coalesced row read).
__global__ __launch_bounds__(256) void k_agg(unsigned short* __restrict__ A,
                                             const int* __restrict__ csr,
                                             const int* __restrict__ off,
                                             const int* __restrict__ cnt) {
    int n = (blockIdx.x * blockDim.x + threadIdx.x) >> 6;
    int lane = threadIdx.x & 63;
    if (n >= N_NODES) return;
    int begin = off[n], deg = cnt[n];
    float ax = 0.f, ay = 0.f;
    int i = 0;
    for (; i + 4 <= deg; i += 4) {
        int s0 = csr[begin + i + 0];
        int s1 = csr[begin + i + 1];
        int s2 = csr[begin + i + 2];
        int s3 = csr[begin + i + 3];
        unsigned u0 = *(const unsigned*)(A + (size_t)s0 * KCAT + F_IN + lane * 2);
        unsigned u1 = *(const unsigned*)(A + (size_t)s1 * KCAT + F_IN + lane * 2);
        unsigned u2 = *(const unsigned*)(A + (size_t)s2 * KCAT + F_IN + lane * 2);
        unsigned u3 = *(const unsigned*)(A + (size_t)s3 * KCAT + F_IN + lane * 2);
        ax += b2f(u0 & 0xffff) + b2f(u1 & 0xffff) + b2f(u2 & 0xffff) + b2f(u3 & 0xffff);
        ay += b2f(u0 >> 16) + b2f(u1 >> 16) + b2f(u2 >> 16) + b2f(u3 >> 16);
    }
    for (; i < deg; ++i) {
        int s0 = csr[begin + i];
        unsigned u0 = *(const unsigned*)(A + (size_t)s0 * KCAT + F_IN + lane * 2);
        ax += b2f(u0 & 0xffff);
        ay += b2f(u0 >> 16);
    }
    float inv = 1.0f / fmaxf((float)deg, 1.0f);
    unsigned lo = f2bf(ax * inv), hi = f2bf(ay * inv);
    *(unsigned*)(A + (size_t)n * KCAT + lane * 2) = lo | (hi << 16);
}

// ------------------------------------------------------------------ fused MFMA: h-GEMM + out-GEMM
// One self-contained wave per 64 nodes. mfma_f32_16x16x32_bf16.
__global__ __launch_bounds__(64) void k_fused(
    const unsigned short* __restrict__ A, const unsigned short* __restrict__ Wc,
    const float* __restrict__ bl, const unsigned short* __restrict__ Wo,
    const float* __restrict__ bout, float* __restrict__ out) {

    __shared__ __align__(16) unsigned short hs[64 * 64];   // 8 KB, XOR-swizzled
    const int nb = blockIdx.x * 64;
    const int lane = threadIdx.x;
    const int lm = lane & 15, lk = lane >> 4;

    // ---------- phase 1: h = relu(A[nodes,256] x Wc[64,256]^T + bl)
    f32x4 acc[4][4];
#pragma unroll
    for (int a = 0; a < 4; ++a)
#pragma unroll
        for (int b = 0; b < 4; ++b) acc[a][b] = f32x4{0.f, 0.f, 0.f, 0.f};

#pragma unroll
    for (int kt = 0; kt < 8; ++kt) {
        const int ko = kt * 32 + lk * 8;
        bf8 af[4], bw[4];
#pragma unroll
        for (int mt = 0; mt < 4; ++mt) {
            int row = nb + mt * 16 + lm;
            if (row >= N_NODES) row = N_NODES - 1;
            af[mt] = *reinterpret_cast<const bf8*>(A + (size_t)row * KCAT + ko);
        }
#pragma unroll
        for (int nt = 0; nt < 4; ++nt)
            bw[nt] = *reinterpret_cast<const bf8*>(Wc + (nt * 16 + lm) * KCAT + ko);
#pragma unroll
        for (int mt = 0; mt < 4; ++mt)
#pragma unroll
            for (int nt = 0; nt < 4; ++nt)
                acc[mt][nt] = __builtin_amdgcn_mfma_f32_16x16x32_bf16(af[mt], bw[nt], acc[mt][nt], 0, 0, 0);
    }

    // epilogue 1: bias + relu, bf16, write transposed-layout LDS tile (swizzled)
#pragma unroll
    for (int nt = 0; nt < 4; ++nt) {
        float bv = bl[nt * 16 + lm];
#pragma unroll
        for (int mt = 0; mt < 4; ++mt)
#pragma unroll
            for (int r = 0; r < 4; ++r) {
                int rowl = mt * 16 + lk * 4 + r;              // local node
                int cb = (nt * 32 + lm * 2) ^ ((rowl & 7) << 4);
                float v = fmaxf(acc[mt][nt][r] + bv, 0.f);
                hs[rowl * 64 + (cb >> 1)] = f2bf(v);
            }
    }
    __syncthreads();

    // ---------- phase 2: out = h[64,64] x Wo[320,64]^T + bout
    bf8 ah[4][2];
#pragma unroll
    for (int mt = 0; mt < 4; ++mt)
#pragma unroll
        for (int k2 = 0; k2 < 2; ++k2) {
            int rowl = mt * 16 + lm;
            int cb = (k2 * 64 + lk * 16) ^ ((rowl & 7) << 4);
            ah[mt][k2] = *reinterpret_cast<const bf8*>(
                reinterpret_cast<const char*>(hs) + rowl * 128 + cb);
        }

    for (int g = 0; g < 5; ++g) {
        f32x4 acc2[4][4];
#pragma unroll
        for (int a = 0; a < 4; ++a)
#pragma unroll
            for (int b = 0; b < 4; ++b) acc2[a][b] = f32x4{0.f, 0.f, 0.f, 0.f};
#pragma unroll
        for (int k2 = 0; k2 < 2; ++k2) {
            bf8 bw[4];
#pragma unroll
            for (int nt = 0; nt < 4; ++nt)
                bw[nt] = *reinterpret_cast<const bf8*>(
                    Wo + (size_t)((g * 4 + nt) * 16 + lm) * HID + k2 * 32 + lk * 8);
#pragma unroll
            for (int mt = 0; mt < 4; ++mt)
#pragma unroll
                for (int nt = 0; nt < 4; ++nt)
                    acc2[mt][nt] = __builtin_amdgcn_mfma_f32_16x16x32_bf16(ah[mt][k2], bw[nt], acc2[mt][nt], 0, 0, 0);
        }
#pragma unroll
        for (int nt = 0; nt < 4; ++nt) {
            int o = (g * 4 + nt) * 16 + lm;
            float bo = (o < OUT_F) ? bout[o] : 0.f;
#pragma unroll
            for (int mt = 0; mt < 4; ++mt)
#pragma unroll
                for (int r = 0; r < 4; ++r) {
                    int node = nb + mt * 16 + lk * 4 + r;
                    if (node < N_NODES && o < OUT_F)
                        out[(size_t)node * OUT_F + o] = acc2[mt][nt][r] + bo;
                }
        }
    }
}

extern "C" void kernel_launch(void* const* d_in, const int* in_sizes, int n_in,
                              void* d_out, int out_size, void* d_ws, size_t ws_size,
                              hipStream_t stream) {
    const float* x    = (const float*)d_in[0];
    const int*   ei   = (const int*)d_in[1];
    const float* Wl   = (const float*)d_in[2];
    const float* bl   = (const float*)d_in[3];
    const float* Wr   = (const float*)d_in[4];
    const float* Wout = (const float*)d_in[5];
    const float* bout = (const float*)d_in[6];
    float* out = (float*)d_out;

    int nE = in_sizes[1] / 2;

    unsigned short* A   = (unsigned short*)d_ws;          // 100000*256*2 = 51.2 MB
    int* csr    = (int*)(A + (size_t)N_NODES * KCAT);     // 6.4 MB
    int* cnt    = csr + nE;
    int* off    = cnt + N_NODES;
    int* cursor = off + N_NODES;
    int* bsum   = cursor + N_NODES;                       // 98 used, 128 reserved
    int* bpre   = bsum + 128;                             // 98 used, 128 reserved
    unsigned short* Wc = (unsigned short*)(bpre + 128);   // 64*256
    unsigned short* Wo = Wc + HID * KCAT;                 // 320*64

    int nbE = (nE + 255) / 256;
    int nbS = (N_NODES + 1023) / 1024;                    // 98

    k_zero<<<(N_NODES + 255) / 256, 256, 0, stream>>>(cnt);
    k_hist<<<nbE, 256, 0, stream>>>(ei, cnt, nE);
    k_scan1<<<nbS, 1024, 0, stream>>>(cnt, bsum);
    k_scan2<<<1, 64, 0, stream>>>(bsum, bpre, nbS);
    k_scan3<<<nbS, 1024, 0, stream>>>(cnt, bpre, off, cursor);
    k_fill<<<nbE, 256, 0, stream>>>(ei, cursor, csr, nE);
    k_cvt<<<(N_NODES * F_IN / 4 + 255) / 256, 256, 0, stream>>>(x, A);
    k_wcvt<<<(HID * KCAT + WO_ROWS * HID + 255) / 256, 256, 0, stream>>>(Wl, Wr, Wout, Wc, Wo);
    k_agg<<<(N_NODES * 64 + 255) / 256, 256, 0, stream>>>(A, csr, off, cnt);
    k_fused<<<(N_NODES + 63) / 64, 64, 0, stream>>>(A, Wc, bl, Wo, bout, out);
}